// Round 1
// baseline (1860.778 us; speedup 1.0000x reference)
//
#include <hip/hip_runtime.h>
#include <math.h>

// Problem constants
#define B_ 256
#define T_ 2000
#define I_ 80
#define H_ 20
#define G_ 80      // 4*H
#define M_ 512000  // B*T

#define LOG2E 1.442695041f

typedef __attribute__((ext_vector_type(2))) float f32x2;

__device__ __forceinline__ f32x2 mk2(float a, float b) { f32x2 r; r.x = a; r.y = b; return r; }

// ---------------------------------------------------------------------------
// GEMM (layer 0, row-major A): XG[row][d*80 + j*4 + g] =
//   pS_g * (sum_k X[row][k]*Wih[d][k][g*20+j] + B[d][g*20+j])
// ---------------------------------------------------------------------------
template<int K>
__global__ __launch_bounds__(256) void gemm_xg(
    const float* __restrict__ X,     // (M, K) row-major
    const float* __restrict__ Wih,   // (2, K, 80)
    const float* __restrict__ Bias,  // (2, 80)
    float* __restrict__ XG,          // (M, 160) permuted+scaled cols
    int M)
{
    constexpr int KC = 40;
    __shared__ float ws[KC][164];
    __shared__ float xs[KC][100];
    __shared__ float bs[160];

    const int tid  = threadIdx.x;
    const int row0 = blockIdx.x * 96;
    const int tx = tid % 20;
    const int ty = tid / 20;
    const bool run = (ty < 12);

    if (tid < 160) {
        int dd = (tid >= 80);
        int r = tid - 80 * dd;
        int j = r >> 2, g = r & 3;
        float sc = (g == 2) ? 2.0f * LOG2E : -LOG2E;
        bs[tid] = sc * Bias[dd * 80 + g * 20 + j];
    }

    int nrows = M - row0; if (nrows > 96) nrows = 96;

    float acc[8][8];
    bool first = true;

    for (int kc = 0; kc < K; kc += KC) {
        for (int idx = tid; idx < KC * 160; idx += 256) {
            int i = idx / 160, cc = idx - 160 * i;
            int dd = (cc >= 80), r = cc - 80 * dd;
            int j = r >> 2, g = r & 3;
            float sc = (g == 2) ? 2.0f * LOG2E : -LOG2E;
            ws[i][cc] = sc * Wih[(dd * K + kc + i) * 80 + g * 20 + j];
        }
        for (int i4 = tid; i4 < (96 * KC) / 4; i4 += 256) {
            int r = i4 / 10;
            int kk = (i4 - 10 * r) * 4;
            float4 v = make_float4(0.f, 0.f, 0.f, 0.f);
            if (r < nrows)
                v = *(const float4*)(X + (long long)(row0 + r) * K + kc + kk);
            xs[kk][r] = v.x; xs[kk + 1][r] = v.y; xs[kk + 2][r] = v.z; xs[kk + 3][r] = v.w;
        }
        __syncthreads();

        if (first) {
            first = false;
            float bv[8];
            #pragma unroll
            for (int cc = 0; cc < 8; ++cc) bv[cc] = bs[tx * 8 + cc];
            #pragma unroll
            for (int r = 0; r < 8; ++r)
                #pragma unroll
                for (int cc = 0; cc < 8; ++cc) acc[r][cc] = bv[cc];
        }

        if (run) {
            #pragma unroll 4
            for (int k = 0; k < KC; ++k) {
                float a[8], bb[8];
                *(float4*)&a[0]  = *(const float4*)&xs[k][ty * 8];
                *(float4*)&a[4]  = *(const float4*)&xs[k][ty * 8 + 4];
                *(float4*)&bb[0] = *(const float4*)&ws[k][tx * 8];
                *(float4*)&bb[4] = *(const float4*)&ws[k][tx * 8 + 4];
                #pragma unroll
                for (int r = 0; r < 8; ++r)
                    #pragma unroll
                    for (int cc = 0; cc < 8; ++cc)
                        acc[r][cc] = fmaf(a[r], bb[cc], acc[r][cc]);
            }
        }
        __syncthreads();
    }

    if (run) {
        #pragma unroll
        for (int r = 0; r < 8; ++r) {
            int row = row0 + ty * 8 + r;
            if (row < M) {
                float* dst = XG + (long long)row * 160 + tx * 8;
                *(float4*)(dst)     = *(float4*)&acc[r][0];
                *(float4*)(dst + 4) = *(float4*)&acc[r][4];
            }
        }
    }
}

// ---------------------------------------------------------------------------
// GEMM (layer 1, TRANSPOSED A): A[row=(b,t)][k] = H0t[(b*40+k)*T + t]
// K=40. Tiles never straddle batches: grid = B * 21, tile = (b, t0..t0+95).
// Staging loads float4 along t (contiguous) — fully coalesced.
// ---------------------------------------------------------------------------
__global__ __launch_bounds__(256) void gemm_xg_tA(
    const float* __restrict__ H0t,   // (B, 40, T)
    const float* __restrict__ Wih,   // (2, 40, 80)
    const float* __restrict__ Bias,  // (2, 80)
    float* __restrict__ XG,          // (M, 160) permuted+scaled cols
    int T)
{
    constexpr int K = 40;
    __shared__ float ws[K][164];
    __shared__ float xs[K][100];
    __shared__ float bs[160];

    const int tid = threadIdx.x;
    const int bb  = blockIdx.x / 21;
    const int tc  = blockIdx.x % 21;
    const int t0  = tc * 96;
    const int tx  = tid % 20;
    const int ty  = tid / 20;
    const bool run = (ty < 12);

    if (tid < 160) {
        int dd = (tid >= 80);
        int r = tid - 80 * dd;
        int j = r >> 2, g = r & 3;
        float sc = (g == 2) ? 2.0f * LOG2E : -LOG2E;
        bs[tid] = sc * Bias[dd * 80 + g * 20 + j];
    }

    int nrows = T - t0; if (nrows > 96) nrows = 96;   // 96 or 80 (both %4==0)

    // stage weights (single K-chunk)
    for (int idx = tid; idx < K * 160; idx += 256) {
        int i = idx / 160, cc = idx - 160 * i;
        int dd = (cc >= 80), r = cc - 80 * dd;
        int j = r >> 2, g = r & 3;
        float sc = (g == 2) ? 2.0f * LOG2E : -LOG2E;
        ws[i][cc] = sc * Wih[(dd * K + i) * 80 + g * 20 + j];
    }
    // stage A^T: xs[k][r] = H0t[(bb*40+k)*T + t0 + r], float4 along r(=t)
    for (int i4 = tid; i4 < K * 24; i4 += 256) {
        int k = i4 / 24;
        int r = (i4 - 24 * k) * 4;
        float4 v = make_float4(0.f, 0.f, 0.f, 0.f);
        if (r < nrows)
            v = *(const float4*)(H0t + ((long long)bb * 40 + k) * T + t0 + r);
        *(float4*)&xs[k][r] = v;
    }
    __syncthreads();

    float acc[8][8];
    {
        float bv[8];
        #pragma unroll
        for (int cc = 0; cc < 8; ++cc) bv[cc] = bs[tx * 8 + cc];
        #pragma unroll
        for (int r = 0; r < 8; ++r)
            #pragma unroll
            for (int cc = 0; cc < 8; ++cc) acc[r][cc] = bv[cc];
    }

    if (run) {
        #pragma unroll 4
        for (int k = 0; k < K; ++k) {
            float a[8], bb2[8];
            *(float4*)&a[0]   = *(const float4*)&xs[k][ty * 8];
            *(float4*)&a[4]   = *(const float4*)&xs[k][ty * 8 + 4];
            *(float4*)&bb2[0] = *(const float4*)&ws[k][tx * 8];
            *(float4*)&bb2[4] = *(const float4*)&ws[k][tx * 8 + 4];
            #pragma unroll
            for (int r = 0; r < 8; ++r)
                #pragma unroll
                for (int cc = 0; cc < 8; ++cc)
                    acc[r][cc] = fmaf(a[r], bb2[cc], acc[r][cc]);
        }

        #pragma unroll
        for (int r = 0; r < 8; ++r) {
            int rr = ty * 8 + r;
            if (rr < nrows) {
                long long row = (long long)bb * T + t0 + rr;
                float* dst = XG + row * 160 + tx * 8;
                *(float4*)(dst)     = *(float4*)&acc[r][0];
                *(float4*)(dst + 4) = *(float4*)&acc[r][4];
            }
        }
    }
}

// ---------------------------------------------------------------------------
// LSTM scan v7 = v6 + BATCHED TRANSPOSED h stores.
// h kept in 4 registers, ONE float4 store per 4 steps to h_out (B, 40, T)
// (contiguous along t per unit) — 4x fewer store events in the vm queue,
// store clusters separated from the prefetch-load clusters.
// Everything else identical to v6.
// ---------------------------------------------------------------------------
__attribute__((amdgpu_waves_per_eu(1)))
__global__ __launch_bounds__(64) void lstm_scan(
    const float* __restrict__ xg,    // (B,T,2,20,4) scaled, unit-major
    const float* __restrict__ w_hh,  // (2, 20, 80) natural (k, g*20+j)
    float* __restrict__ h_out,       // (B, 40, T): [(b*40 + d*20 + j)*T + t]
    int T)
{
    const int b    = blockIdx.x;          // 0..255
    const int lane = threadIdx.x & 63;
    const int d    = lane >> 5;           // 0 = fwd (lanes 0-31), 1 = bwd
    const int j    = lane & 31;
    const bool act_lane = (j < H_);
    const int jj   = act_lane ? j : 0;
    const bool isB = (d == 1);

    // Pre-scaled packed recurrent weights (per-half values in same registers)
    f32x2 w[4][10];
    const float* wb = w_hh + d * (H_ * G_);
    #pragma unroll
    for (int g = 0; g < 4; ++g) {
        const float sc = (g == 2) ? 2.0f * LOG2E : -LOG2E;
        #pragma unroll
        for (int i = 0; i < 10; ++i)
            w[g][i] = mk2(sc * wb[(2 * i) * G_ + g * 20 + jj],
                          sc * wb[(2 * i + 1) * G_ + g * 20 + jj]);
    }

    // Wave-uniform h for both sequences (SGPRs via readlane)
    float shA[20], shB[20];
    #pragma unroll
    for (int k = 0; k < 20; ++k) { shA[k] = 0.f; shB[k] = 0.f; }
    float c = 0.f;

    const int t0    = isB ? (T - 1) : 0;
    const int rstep = isB ? -160 : 160;
    const float* pf = xg + ((long long)(b * T + t0) * 2 + d) * 80 + 4 * jj;

    // transposed h store pointer: group of 4 t's, 16B aligned
    float* hp = h_out + ((long long)b * 40 + d * 20 + jj) * T + (isB ? T - 4 : 0);
    const int hgstep = isB ? -4 : 4;

    constexpr int PF = 8;
    float4 px[PF];
    #pragma unroll
    for (int s = 0; s < PF; ++s) { px[s] = *(const float4*)pf; pf += rstep; }

    float hq0 = 0.f, hq1 = 0.f, hq2 = 0.f, hq3 = 0.f;

    for (int tb = 0; tb < T; tb += PF) {
        #pragma unroll
        for (int s = 0; s < PF; ++s) {
            const float4 v = px[s];
            px[s] = *(const float4*)pf; pf += rstep;   // prefetch t+PF

            // 8 independent pk-chains (4 gates x 2 seqs), depth 10
            f32x2 aA[4], aB[4];
            aA[0] = mk2(v.x, 0.f); aA[1] = mk2(v.y, 0.f);
            aA[2] = mk2(v.z, 0.f); aA[3] = mk2(v.w, 0.f);
            #pragma unroll
            for (int g = 0; g < 4; ++g) aB[g] = aA[g];
            #pragma unroll
            for (int i = 0; i < 10; ++i) {
                const f32x2 ha = mk2(shA[2 * i], shA[2 * i + 1]);
                const f32x2 hb = mk2(shB[2 * i], shB[2 * i + 1]);
                #pragma unroll
                for (int g = 0; g < 4; ++g) {
                    aA[g] = __builtin_elementwise_fma(w[g][i], ha, aA[g]);
                    aB[g] = __builtin_elementwise_fma(w[g][i], hb, aB[g]);
                }
            }
            float m[4];
            #pragma unroll
            for (int g = 0; g < 4; ++g) {
                const float sA = aA[g].x + aA[g].y;
                const float sB = aB[g].x + aB[g].y;
                m[g] = isB ? sB : sA;
            }

            const float gi = __builtin_amdgcn_rcpf(1.0f + __builtin_amdgcn_exp2f(m[0]));
            const float gf = __builtin_amdgcn_rcpf(1.0f + __builtin_amdgcn_exp2f(m[1]));
            const float gg = fmaf(-2.0f,
                __builtin_amdgcn_rcpf(1.0f + __builtin_amdgcn_exp2f(m[2])), 1.0f);
            const float go = __builtin_amdgcn_rcpf(1.0f + __builtin_amdgcn_exp2f(m[3]));

            c = fmaf(gf, c, gi * gg);
            const float th = fmaf(-2.0f,
                __builtin_amdgcn_rcpf(1.0f + __builtin_amdgcn_exp2f(2.0f * LOG2E * c)), 1.0f);
            const float hj = go * th;

            // buffer h (phase = s&3); one float4 store per 4 steps
            if constexpr (true) {
                const int p = s & 3;
                if (p == 0) hq0 = hj;
                else if (p == 1) hq1 = hj;
                else if (p == 2) hq2 = hj;
                else {
                    hq3 = hj;
                    float4 sv;   // bwd wrote t descending -> reverse for memory order
                    sv.x = isB ? hq3 : hq0;
                    sv.y = isB ? hq2 : hq1;
                    sv.z = isB ? hq1 : hq2;
                    sv.w = isB ? hq0 : hq3;
                    if (act_lane) *(float4*)hp = sv;
                    hp += hgstep;
                }
            }

            // broadcast both sequences' h into wave-uniform copies
            #pragma unroll
            for (int k = 0; k < 20; ++k) {
                shA[k] = __uint_as_float(__builtin_amdgcn_readlane(__float_as_uint(hj), k));
                shB[k] = __uint_as_float(__builtin_amdgcn_readlane(__float_as_uint(hj), 32 + k));
            }
        }
    }
}

// ---------------------------------------------------------------------------
// FC over transposed h: out[b*T+t] = sum_u H1t[(b*40+u)*T+t]*w[u] + bias.
// Fully coalesced float4 along t. grid (B, 2): chunk c covers t in
// [c*1024, ...): c=0 -> 256 threads x4, c=1 -> 244 threads x4 (total 2000).
// ---------------------------------------------------------------------------
__global__ __launch_bounds__(256) void fc_t(
    const float* __restrict__ H1t,  // (B, 40, T)
    const float* __restrict__ Wf,   // (40,)
    const float* __restrict__ Bf,   // (1,)
    float* __restrict__ Out,        // (B, T)
    int T)
{
    const int b   = blockIdx.x;
    const int t   = blockIdx.y * 1024 + threadIdx.x * 4;
    if (t + 3 >= T + 3) return;      // t <= T-4 guard below
    if (t > T - 4) return;

    const float bias = Bf[0];
    float4 acc = make_float4(bias, bias, bias, bias);
    const float* base = H1t + (long long)b * 40 * T + t;
    #pragma unroll 8
    for (int u = 0; u < 40; ++u) {
        const float wv = Wf[u];
        const float4 hv = *(const float4*)(base + (long long)u * T);
        acc.x = fmaf(hv.x, wv, acc.x);
        acc.y = fmaf(hv.y, wv, acc.y);
        acc.z = fmaf(hv.z, wv, acc.z);
        acc.w = fmaf(hv.w, wv, acc.w);
    }
    *(float4*)(Out + (long long)b * T + t) = acc;
}

// ---------------------------------------------------------------------------
extern "C" void kernel_launch(void* const* d_in, const int* in_sizes, int n_in,
                              void* d_out, int out_size, void* d_ws, size_t ws_size,
                              hipStream_t stream) {
    const float* x     = (const float*)d_in[0];
    const float* wih0  = (const float*)d_in[1];
    const float* whh0  = (const float*)d_in[2];
    const float* b0    = (const float*)d_in[3];
    const float* wih1  = (const float*)d_in[4];
    const float* whh1  = (const float*)d_in[5];
    const float* b1    = (const float*)d_in[6];
    const float* fcw   = (const float*)d_in[7];
    const float* fcb   = (const float*)d_in[8];
    float* out = (float*)d_out;

    // Workspace (floats): 2048-float pads around xg for the scan's
    // unconditional ±8-step prefetch.
    float* ws = (float*)d_ws;
    float* xg  = ws + 2048;                  // B*T*2*80 = 81,920,000 floats
    float* h0t = xg + 81920000LL + 2048;     // B*40*T   = 20,480,000 floats
    float* h1t = h0t + 20480000LL;           // B*40*T   = 20,480,000 floats

    const int M = M_;
    const int gemm_grid = (M + 95) / 96;     // 5334

    // Layer 0 (row-major A)
    gemm_xg<80><<<dim3(gemm_grid), dim3(256), 0, stream>>>(x, wih0, b0, xg, M);
    lstm_scan<<<dim3(B_), dim3(64), 0, stream>>>(xg, whh0, h0t, T_);
    // Layer 1 (transposed A)
    gemm_xg_tA<<<dim3(B_ * 21), dim3(256), 0, stream>>>(h0t, whh1 == nullptr ? b1 : wih1, b1, xg, T_);
    lstm_scan<<<dim3(B_), dim3(64), 0, stream>>>(xg, whh1, h1t, T_);
    // FC (transposed input, coalesced)
    fc_t<<<dim3(B_, 2), dim3(256), 0, stream>>>(h1t, fcw, fcb, out, T_);
}

// Round 2
// 1549.390 us; speedup vs baseline: 1.2010x; 1.2010x over previous
//
#include <hip/hip_runtime.h>
#include <math.h>

// Problem constants
#define B_ 256
#define T_ 2000
#define I_ 80
#define H_ 20
#define G_ 80      // 4*H
#define M_ 512000  // B*T

#define LOG2E 1.442695041f

typedef __attribute__((ext_vector_type(2))) float f32x2;

__device__ __forceinline__ f32x2 mk2(float a, float b) { f32x2 r; r.x = a; r.y = b; return r; }

// ---------------------------------------------------------------------------
// GEMM (layer 0, row-major A): XG[row][d*80 + j*4 + g] =
//   pS_g * (sum_k X[row][k]*Wih[d][k][g*20+j] + B[d][g*20+j])
// ---------------------------------------------------------------------------
template<int K>
__global__ __launch_bounds__(256) void gemm_xg(
    const float* __restrict__ X,     // (M, K) row-major
    const float* __restrict__ Wih,   // (2, K, 80)
    const float* __restrict__ Bias,  // (2, 80)
    float* __restrict__ XG,          // (M, 160) permuted+scaled cols
    int M)
{
    constexpr int KC = 40;
    __shared__ float ws[KC][164];
    __shared__ float xs[KC][100];
    __shared__ float bs[160];

    const int tid  = threadIdx.x;
    const int row0 = blockIdx.x * 96;
    const int tx = tid % 20;
    const int ty = tid / 20;
    const bool run = (ty < 12);

    if (tid < 160) {
        int dd = (tid >= 80);
        int r = tid - 80 * dd;
        int j = r >> 2, g = r & 3;
        float sc = (g == 2) ? 2.0f * LOG2E : -LOG2E;
        bs[tid] = sc * Bias[dd * 80 + g * 20 + j];
    }

    int nrows = M - row0; if (nrows > 96) nrows = 96;

    float acc[8][8];
    bool first = true;

    for (int kc = 0; kc < K; kc += KC) {
        for (int idx = tid; idx < KC * 160; idx += 256) {
            int i = idx / 160, cc = idx - 160 * i;
            int dd = (cc >= 80), r = cc - 80 * dd;
            int j = r >> 2, g = r & 3;
            float sc = (g == 2) ? 2.0f * LOG2E : -LOG2E;
            ws[i][cc] = sc * Wih[(dd * K + kc + i) * 80 + g * 20 + j];
        }
        for (int i4 = tid; i4 < (96 * KC) / 4; i4 += 256) {
            int r = i4 / 10;
            int kk = (i4 - 10 * r) * 4;
            float4 v = make_float4(0.f, 0.f, 0.f, 0.f);
            if (r < nrows)
                v = *(const float4*)(X + (long long)(row0 + r) * K + kc + kk);
            xs[kk][r] = v.x; xs[kk + 1][r] = v.y; xs[kk + 2][r] = v.z; xs[kk + 3][r] = v.w;
        }
        __syncthreads();

        if (first) {
            first = false;
            float bv[8];
            #pragma unroll
            for (int cc = 0; cc < 8; ++cc) bv[cc] = bs[tx * 8 + cc];
            #pragma unroll
            for (int r = 0; r < 8; ++r)
                #pragma unroll
                for (int cc = 0; cc < 8; ++cc) acc[r][cc] = bv[cc];
        }

        if (run) {
            #pragma unroll 4
            for (int k = 0; k < KC; ++k) {
                float a[8], bb[8];
                *(float4*)&a[0]  = *(const float4*)&xs[k][ty * 8];
                *(float4*)&a[4]  = *(const float4*)&xs[k][ty * 8 + 4];
                *(float4*)&bb[0] = *(const float4*)&ws[k][tx * 8];
                *(float4*)&bb[4] = *(const float4*)&ws[k][tx * 8 + 4];
                #pragma unroll
                for (int r = 0; r < 8; ++r)
                    #pragma unroll
                    for (int cc = 0; cc < 8; ++cc)
                        acc[r][cc] = fmaf(a[r], bb[cc], acc[r][cc]);
            }
        }
        __syncthreads();
    }

    if (run) {
        #pragma unroll
        for (int r = 0; r < 8; ++r) {
            int row = row0 + ty * 8 + r;
            if (row < M) {
                float* dst = XG + (long long)row * 160 + tx * 8;
                *(float4*)(dst)     = *(float4*)&acc[r][0];
                *(float4*)(dst + 4) = *(float4*)&acc[r][4];
            }
        }
    }
}

// ---------------------------------------------------------------------------
// GEMM (layer 1, TRANSPOSED A): A[row=(b,t)][k] = H0t[(b*40+k)*T + t]
// K=40. Tiles never straddle batches: grid = B * 21, tile = (b, t0..t0+95).
// ---------------------------------------------------------------------------
__global__ __launch_bounds__(256) void gemm_xg_tA(
    const float* __restrict__ H0t,   // (B, 40, T)
    const float* __restrict__ Wih,   // (2, 40, 80)
    const float* __restrict__ Bias,  // (2, 80)
    float* __restrict__ XG,          // (M, 160) permuted+scaled cols
    int T)
{
    constexpr int K = 40;
    __shared__ float ws[K][164];
    __shared__ float xs[K][100];
    __shared__ float bs[160];

    const int tid = threadIdx.x;
    const int bb  = blockIdx.x / 21;
    const int tc  = blockIdx.x % 21;
    const int t0  = tc * 96;
    const int tx  = tid % 20;
    const int ty  = tid / 20;
    const bool run = (ty < 12);

    if (tid < 160) {
        int dd = (tid >= 80);
        int r = tid - 80 * dd;
        int j = r >> 2, g = r & 3;
        float sc = (g == 2) ? 2.0f * LOG2E : -LOG2E;
        bs[tid] = sc * Bias[dd * 80 + g * 20 + j];
    }

    int nrows = T - t0; if (nrows > 96) nrows = 96;   // 96 or 80 (both %4==0)

    // stage weights (single K-chunk)
    for (int idx = tid; idx < K * 160; idx += 256) {
        int i = idx / 160, cc = idx - 160 * i;
        int dd = (cc >= 80), r = cc - 80 * dd;
        int j = r >> 2, g = r & 3;
        float sc = (g == 2) ? 2.0f * LOG2E : -LOG2E;
        ws[i][cc] = sc * Wih[(dd * K + i) * 80 + g * 20 + j];
    }
    // stage A^T: xs[k][r] = H0t[(bb*40+k)*T + t0 + r], float4 along r(=t)
    for (int i4 = tid; i4 < K * 24; i4 += 256) {
        int k = i4 / 24;
        int r = (i4 - 24 * k) * 4;
        float4 v = make_float4(0.f, 0.f, 0.f, 0.f);
        if (r < nrows)
            v = *(const float4*)(H0t + ((long long)bb * 40 + k) * T + t0 + r);
        *(float4*)&xs[k][r] = v;
    }
    __syncthreads();

    float acc[8][8];
    {
        float bv[8];
        #pragma unroll
        for (int cc = 0; cc < 8; ++cc) bv[cc] = bs[tx * 8 + cc];
        #pragma unroll
        for (int r = 0; r < 8; ++r)
            #pragma unroll
            for (int cc = 0; cc < 8; ++cc) acc[r][cc] = bv[cc];
    }

    if (run) {
        #pragma unroll 4
        for (int k = 0; k < K; ++k) {
            float a[8], bb2[8];
            *(float4*)&a[0]   = *(const float4*)&xs[k][ty * 8];
            *(float4*)&a[4]   = *(const float4*)&xs[k][ty * 8 + 4];
            *(float4*)&bb2[0] = *(const float4*)&ws[k][tx * 8];
            *(float4*)&bb2[4] = *(const float4*)&ws[k][tx * 8 + 4];
            #pragma unroll
            for (int r = 0; r < 8; ++r)
                #pragma unroll
                for (int cc = 0; cc < 8; ++cc)
                    acc[r][cc] = fmaf(a[r], bb2[cc], acc[r][cc]);
        }

        #pragma unroll
        for (int r = 0; r < 8; ++r) {
            int rr = ty * 8 + r;
            if (rr < nrows) {
                long long row = (long long)bb * T + t0 + rr;
                float* dst = XG + row * 160 + tx * 8;
                *(float4*)(dst)     = *(float4*)&acc[r][0];
                *(float4*)(dst + 4) = *(float4*)&acc[r][4];
            }
        }
    }
}

// ---------------------------------------------------------------------------
// LSTM scan v8 = v7 with ds_swizzle broadcast instead of readlane SGPRs.
//
// v7 kept h wave-uniform in SGPRs (40 readlanes/step) which forced EVERY
// lane to compute BOTH directions' gate chains (80 pk-FMAs, half discarded
// via isB select). v8 broadcasts h per-lane with ds_swizzle_b32 BitMode
// offset k<<5 (= "read lane k of own 32-lane half"): fwd lanes see fwd h,
// bwd lanes see bwd h, in VGPRs. Each lane now runs ONE chain:
//   40 pk-FMAs + 20 swizzles/step  (was 80 pk-FMAs + 40 readlanes + selects)
// amdgpu_waves_per_eu(1,1): exactly 1 wave/EU -> allocator may use the whole
// register file (w[80 floats] + px[32] + hh[20] all stay resident).
// ---------------------------------------------------------------------------
__attribute__((amdgpu_waves_per_eu(1, 1)))
__global__ __launch_bounds__(64) void lstm_scan(
    const float* __restrict__ xg,    // (B,T,2,20,4) scaled, unit-major
    const float* __restrict__ w_hh,  // (2, 20, 80) natural (k, g*20+j)
    float* __restrict__ h_out,       // (B, 40, T): [(b*40 + d*20 + j)*T + t]
    int T)
{
    const int b    = blockIdx.x;          // 0..255
    const int lane = threadIdx.x & 63;
    const int d    = lane >> 5;           // 0 = fwd (lanes 0-31), 1 = bwd
    const int j    = lane & 31;
    const bool act_lane = (j < H_);
    const int jj   = act_lane ? j : 0;
    const bool isB = (d == 1);

    // Pre-scaled packed recurrent weights for OWN direction
    f32x2 w[4][10];
    const float* wb = w_hh + d * (H_ * G_);
    #pragma unroll
    for (int g = 0; g < 4; ++g) {
        const float sc = (g == 2) ? 2.0f * LOG2E : -LOG2E;
        #pragma unroll
        for (int i = 0; i < 10; ++i)
            w[g][i] = mk2(sc * wb[(2 * i) * G_ + g * 20 + jj],
                          sc * wb[(2 * i + 1) * G_ + g * 20 + jj]);
    }

    // Per-lane packed h of OWN direction (pairs h[2i], h[2i+1])
    f32x2 hh[10];
    #pragma unroll
    for (int i = 0; i < 10; ++i) hh[i] = mk2(0.f, 0.f);
    float c = 0.f;

    const int t0    = isB ? (T - 1) : 0;
    const int rstep = isB ? -160 : 160;
    const float* pf = xg + ((long long)(b * T + t0) * 2 + d) * 80 + 4 * jj;

    // transposed h store pointer: group of 4 t's, 16B aligned
    float* hp = h_out + ((long long)b * 40 + d * 20 + jj) * T + (isB ? T - 4 : 0);
    const int hgstep = isB ? -4 : 4;

    constexpr int PF = 8;
    float4 px[PF];
    #pragma unroll
    for (int s = 0; s < PF; ++s) { px[s] = *(const float4*)pf; pf += rstep; }

    float hq0 = 0.f, hq1 = 0.f, hq2 = 0.f, hq3 = 0.f;

    for (int tb = 0; tb < T; tb += PF) {
        #pragma unroll
        for (int s = 0; s < PF; ++s) {
            const float4 v = px[s];
            px[s] = *(const float4*)pf; pf += rstep;   // prefetch t+PF

            // 4 independent pk-chains (4 gates, own direction), depth 10
            f32x2 a0 = mk2(v.x, 0.f);
            f32x2 a1 = mk2(v.y, 0.f);
            f32x2 a2 = mk2(v.z, 0.f);
            f32x2 a3 = mk2(v.w, 0.f);
            #pragma unroll
            for (int i = 0; i < 10; ++i) {
                a0 = __builtin_elementwise_fma(w[0][i], hh[i], a0);
                a1 = __builtin_elementwise_fma(w[1][i], hh[i], a1);
                a2 = __builtin_elementwise_fma(w[2][i], hh[i], a2);
                a3 = __builtin_elementwise_fma(w[3][i], hh[i], a3);
            }
            const float m0 = a0.x + a0.y;
            const float m1 = a1.x + a1.y;
            const float m2 = a2.x + a2.y;
            const float m3 = a3.x + a3.y;

            const float gi = __builtin_amdgcn_rcpf(1.0f + __builtin_amdgcn_exp2f(m0));
            const float gf = __builtin_amdgcn_rcpf(1.0f + __builtin_amdgcn_exp2f(m1));
            const float gg = fmaf(-2.0f,
                __builtin_amdgcn_rcpf(1.0f + __builtin_amdgcn_exp2f(m2)), 1.0f);
            const float go = __builtin_amdgcn_rcpf(1.0f + __builtin_amdgcn_exp2f(m3));

            c = fmaf(gf, c, gi * gg);
            const float th = fmaf(-2.0f,
                __builtin_amdgcn_rcpf(1.0f + __builtin_amdgcn_exp2f(2.0f * LOG2E * c)), 1.0f);
            const float hj = go * th;

            // buffer h (phase = s&3); one float4 store per 4 steps
            {
                const int p = s & 3;
                if (p == 0) hq0 = hj;
                else if (p == 1) hq1 = hj;
                else if (p == 2) hq2 = hj;
                else {
                    hq3 = hj;
                    float4 sv;   // bwd wrote t descending -> reverse for memory order
                    sv.x = isB ? hq3 : hq0;
                    sv.y = isB ? hq2 : hq1;
                    sv.z = isB ? hq1 : hq2;
                    sv.w = isB ? hq0 : hq3;
                    if (act_lane) *(float4*)hp = sv;
                    hp += hgstep;
                }
            }

            // broadcast own-direction h into per-lane packed pairs:
            // ds_swizzle BitMode offset k<<5 = read lane k of own 32-half
            {
                const int hu = (int)__float_as_uint(hj);
#define SWZF(kk) __uint_as_float((unsigned)__builtin_amdgcn_ds_swizzle(hu, ((kk) << 5)))
                hh[0] = mk2(SWZF(0),  SWZF(1));
                hh[1] = mk2(SWZF(2),  SWZF(3));
                hh[2] = mk2(SWZF(4),  SWZF(5));
                hh[3] = mk2(SWZF(6),  SWZF(7));
                hh[4] = mk2(SWZF(8),  SWZF(9));
                hh[5] = mk2(SWZF(10), SWZF(11));
                hh[6] = mk2(SWZF(12), SWZF(13));
                hh[7] = mk2(SWZF(14), SWZF(15));
                hh[8] = mk2(SWZF(16), SWZF(17));
                hh[9] = mk2(SWZF(18), SWZF(19));
#undef SWZF
            }
        }
    }
}

// ---------------------------------------------------------------------------
// FC over transposed h: out[b*T+t] = sum_u H1t[(b*40+u)*T+t]*w[u] + bias.
// ---------------------------------------------------------------------------
__global__ __launch_bounds__(256) void fc_t(
    const float* __restrict__ H1t,  // (B, 40, T)
    const float* __restrict__ Wf,   // (40,)
    const float* __restrict__ Bf,   // (1,)
    float* __restrict__ Out,        // (B, T)
    int T)
{
    const int b   = blockIdx.x;
    const int t   = blockIdx.y * 1024 + threadIdx.x * 4;
    if (t > T - 4) return;

    const float bias = Bf[0];
    float4 acc = make_float4(bias, bias, bias, bias);
    const float* base = H1t + (long long)b * 40 * T + t;
    #pragma unroll 8
    for (int u = 0; u < 40; ++u) {
        const float wv = Wf[u];
        const float4 hv = *(const float4*)(base + (long long)u * T);
        acc.x = fmaf(hv.x, wv, acc.x);
        acc.y = fmaf(hv.y, wv, acc.y);
        acc.z = fmaf(hv.z, wv, acc.z);
        acc.w = fmaf(hv.w, wv, acc.w);
    }
    *(float4*)(Out + (long long)b * T + t) = acc;
}

// ---------------------------------------------------------------------------
extern "C" void kernel_launch(void* const* d_in, const int* in_sizes, int n_in,
                              void* d_out, int out_size, void* d_ws, size_t ws_size,
                              hipStream_t stream) {
    const float* x     = (const float*)d_in[0];
    const float* wih0  = (const float*)d_in[1];
    const float* whh0  = (const float*)d_in[2];
    const float* b0    = (const float*)d_in[3];
    const float* wih1  = (const float*)d_in[4];
    const float* whh1  = (const float*)d_in[5];
    const float* b1    = (const float*)d_in[6];
    const float* fcw   = (const float*)d_in[7];
    const float* fcb   = (const float*)d_in[8];
    float* out = (float*)d_out;

    // Workspace (floats): 2048-float pads around xg for the scan's
    // unconditional ±8-step prefetch.
    float* ws = (float*)d_ws;
    float* xg  = ws + 2048;                  // B*T*2*80 = 81,920,000 floats
    float* h0t = xg + 81920000LL + 2048;     // B*40*T   = 20,480,000 floats
    float* h1t = h0t + 20480000LL;           // B*40*T   = 20,480,000 floats

    const int M = M_;
    const int gemm_grid = (M + 95) / 96;     // 5334

    // Layer 0 (row-major A)
    gemm_xg<80><<<dim3(gemm_grid), dim3(256), 0, stream>>>(x, wih0, b0, xg, M);
    lstm_scan<<<dim3(B_), dim3(64), 0, stream>>>(xg, whh0, h0t, T_);
    // Layer 1 (transposed A)
    gemm_xg_tA<<<dim3(B_ * 21), dim3(256), 0, stream>>>(h0t, wih1, b1, xg, T_);
    lstm_scan<<<dim3(B_), dim3(64), 0, stream>>>(xg, whh1, h1t, T_);
    // FC (transposed input, coalesced)
    fc_t<<<dim3(B_, 2), dim3(256), 0, stream>>>(h1t, fcw, fcb, out, T_);
}

// Round 3
// 1533.416 us; speedup vs baseline: 1.2135x; 1.0104x over previous
//
#include <hip/hip_runtime.h>
#include <math.h>

// Problem constants
#define B_ 256
#define T_ 2000
#define I_ 80
#define H_ 20
#define G_ 80      // 4*H
#define M_ 512000  // B*T

#define LOG2E 1.442695041f

typedef __attribute__((ext_vector_type(2))) float f32x2;

__device__ __forceinline__ f32x2 mk2(float a, float b) { f32x2 r; r.x = a; r.y = b; return r; }

// ---------------------------------------------------------------------------
// GEMM (layer 0, row-major A): XG[row][d*80 + j*4 + g] =
//   pS_g * (sum_k X[row][k]*Wih[d][k][g*20+j] + B[d][g*20+j])
// ---------------------------------------------------------------------------
template<int K>
__global__ __launch_bounds__(256) void gemm_xg(
    const float* __restrict__ X,     // (M, K) row-major
    const float* __restrict__ Wih,   // (2, K, 80)
    const float* __restrict__ Bias,  // (2, 80)
    float* __restrict__ XG,          // (M, 160) permuted+scaled cols
    int M)
{
    constexpr int KC = 40;
    __shared__ float ws[KC][164];
    __shared__ float xs[KC][100];
    __shared__ float bs[160];

    const int tid  = threadIdx.x;
    const int row0 = blockIdx.x * 96;
    const int tx = tid % 20;
    const int ty = tid / 20;
    const bool run = (ty < 12);

    if (tid < 160) {
        int dd = (tid >= 80);
        int r = tid - 80 * dd;
        int j = r >> 2, g = r & 3;
        float sc = (g == 2) ? 2.0f * LOG2E : -LOG2E;
        bs[tid] = sc * Bias[dd * 80 + g * 20 + j];
    }

    int nrows = M - row0; if (nrows > 96) nrows = 96;

    float acc[8][8];
    bool first = true;

    for (int kc = 0; kc < K; kc += KC) {
        for (int idx = tid; idx < KC * 160; idx += 256) {
            int i = idx / 160, cc = idx - 160 * i;
            int dd = (cc >= 80), r = cc - 80 * dd;
            int j = r >> 2, g = r & 3;
            float sc = (g == 2) ? 2.0f * LOG2E : -LOG2E;
            ws[i][cc] = sc * Wih[(dd * K + kc + i) * 80 + g * 20 + j];
        }
        for (int i4 = tid; i4 < (96 * KC) / 4; i4 += 256) {
            int r = i4 / 10;
            int kk = (i4 - 10 * r) * 4;
            float4 v = make_float4(0.f, 0.f, 0.f, 0.f);
            if (r < nrows)
                v = *(const float4*)(X + (long long)(row0 + r) * K + kc + kk);
            xs[kk][r] = v.x; xs[kk + 1][r] = v.y; xs[kk + 2][r] = v.z; xs[kk + 3][r] = v.w;
        }
        __syncthreads();

        if (first) {
            first = false;
            float bv[8];
            #pragma unroll
            for (int cc = 0; cc < 8; ++cc) bv[cc] = bs[tx * 8 + cc];
            #pragma unroll
            for (int r = 0; r < 8; ++r)
                #pragma unroll
                for (int cc = 0; cc < 8; ++cc) acc[r][cc] = bv[cc];
        }

        if (run) {
            #pragma unroll 4
            for (int k = 0; k < KC; ++k) {
                float a[8], bb[8];
                *(float4*)&a[0]  = *(const float4*)&xs[k][ty * 8];
                *(float4*)&a[4]  = *(const float4*)&xs[k][ty * 8 + 4];
                *(float4*)&bb[0] = *(const float4*)&ws[k][tx * 8];
                *(float4*)&bb[4] = *(const float4*)&ws[k][tx * 8 + 4];
                #pragma unroll
                for (int r = 0; r < 8; ++r)
                    #pragma unroll
                    for (int cc = 0; cc < 8; ++cc)
                        acc[r][cc] = fmaf(a[r], bb[cc], acc[r][cc]);
            }
        }
        __syncthreads();
    }

    if (run) {
        #pragma unroll
        for (int r = 0; r < 8; ++r) {
            int row = row0 + ty * 8 + r;
            if (row < M) {
                float* dst = XG + (long long)row * 160 + tx * 8;
                *(float4*)(dst)     = *(float4*)&acc[r][0];
                *(float4*)(dst + 4) = *(float4*)&acc[r][4];
            }
        }
    }
}

// ---------------------------------------------------------------------------
// GEMM (layer 1, TRANSPOSED A): A[row=(b,t)][k] = H0t[(b*40+k)*T + t]
// K=40. Tiles never straddle batches: grid = B * 21, tile = (b, t0..t0+95).
// ---------------------------------------------------------------------------
__global__ __launch_bounds__(256) void gemm_xg_tA(
    const float* __restrict__ H0t,   // (B, 40, T)
    const float* __restrict__ Wih,   // (2, 40, 80)
    const float* __restrict__ Bias,  // (2, 80)
    float* __restrict__ XG,          // (M, 160) permuted+scaled cols
    int T)
{
    constexpr int K = 40;
    __shared__ float ws[K][164];
    __shared__ float xs[K][100];
    __shared__ float bs[160];

    const int tid = threadIdx.x;
    const int bb  = blockIdx.x / 21;
    const int tc  = blockIdx.x % 21;
    const int t0  = tc * 96;
    const int tx  = tid % 20;
    const int ty  = tid / 20;
    const bool run = (ty < 12);

    if (tid < 160) {
        int dd = (tid >= 80);
        int r = tid - 80 * dd;
        int j = r >> 2, g = r & 3;
        float sc = (g == 2) ? 2.0f * LOG2E : -LOG2E;
        bs[tid] = sc * Bias[dd * 80 + g * 20 + j];
    }

    int nrows = T - t0; if (nrows > 96) nrows = 96;   // 96 or 80 (both %4==0)

    // stage weights (single K-chunk)
    for (int idx = tid; idx < K * 160; idx += 256) {
        int i = idx / 160, cc = idx - 160 * i;
        int dd = (cc >= 80), r = cc - 80 * dd;
        int j = r >> 2, g = r & 3;
        float sc = (g == 2) ? 2.0f * LOG2E : -LOG2E;
        ws[i][cc] = sc * Wih[(dd * K + i) * 80 + g * 20 + j];
    }
    // stage A^T: xs[k][r] = H0t[(bb*40+k)*T + t0 + r], float4 along r(=t)
    for (int i4 = tid; i4 < K * 24; i4 += 256) {
        int k = i4 / 24;
        int r = (i4 - 24 * k) * 4;
        float4 v = make_float4(0.f, 0.f, 0.f, 0.f);
        if (r < nrows)
            v = *(const float4*)(H0t + ((long long)bb * 40 + k) * T + t0 + r);
        *(float4*)&xs[k][r] = v;
    }
    __syncthreads();

    float acc[8][8];
    {
        float bv[8];
        #pragma unroll
        for (int cc = 0; cc < 8; ++cc) bv[cc] = bs[tx * 8 + cc];
        #pragma unroll
        for (int r = 0; r < 8; ++r)
            #pragma unroll
            for (int cc = 0; cc < 8; ++cc) acc[r][cc] = bv[cc];
    }

    if (run) {
        #pragma unroll 4
        for (int k = 0; k < K; ++k) {
            float a[8], bb2[8];
            *(float4*)&a[0]   = *(const float4*)&xs[k][ty * 8];
            *(float4*)&a[4]   = *(const float4*)&xs[k][ty * 8 + 4];
            *(float4*)&bb2[0] = *(const float4*)&ws[k][tx * 8];
            *(float4*)&bb2[4] = *(const float4*)&ws[k][tx * 8 + 4];
            #pragma unroll
            for (int r = 0; r < 8; ++r)
                #pragma unroll
                for (int cc = 0; cc < 8; ++cc)
                    acc[r][cc] = fmaf(a[r], bb2[cc], acc[r][cc]);
        }

        #pragma unroll
        for (int r = 0; r < 8; ++r) {
            int rr = ty * 8 + r;
            if (rr < nrows) {
                long long row = (long long)bb * T + t0 + rr;
                float* dst = XG + row * 160 + tx * 8;
                *(float4*)(dst)     = *(float4*)&acc[r][0];
                *(float4*)(dst + 4) = *(float4*)&acc[r][4];
            }
        }
    }
}

// ---------------------------------------------------------------------------
// LSTM scan v9: ONE DIRECTION PER WAVE (grid = B*2, 2 waves/CU).
//
// v8's ds_swizzle broadcast cost a ~120-150cy LDS round-trip on the serial
// recurrence path every step. With one direction per wave, h is WAVE-UNIFORM:
// broadcast via 20 v_readlane -> SGPRs (latency ~10cy, no LDS). Instruction
// count per wave is unchanged vs v8 (the matvec/tail were never shared
// across directions), and we have 512 sequences for 256 CUs, so doubling
// wave count is free. Gate dot-products split into 2 depth-5 chains to
// halve FMA dependency latency.
// ---------------------------------------------------------------------------
__attribute__((amdgpu_waves_per_eu(1, 1)))
__global__ __launch_bounds__(64) void lstm_scan(
    const float* __restrict__ xg,    // (B,T,2,20,4) scaled, unit-major
    const float* __restrict__ w_hh,  // (2, 20, 80) natural (k, g*20+j)
    float* __restrict__ h_out,       // (B, 40, T): [(b*40 + d*20 + j)*T + t]
    int T)
{
    const int bd   = blockIdx.x;          // 0..511
    const int b    = bd >> 1;
    const int d    = bd & 1;
    const int lane = threadIdx.x & 63;
    const int j    = lane & 31;
    const bool act_lane = (lane < H_);    // lanes 0..19 do real units
    const int jj   = (j < H_) ? j : 0;
    const bool isB = (d == 1);

    // Pre-scaled packed recurrent weights, k split into two depth-5 chains:
    // w[g][i]   covers k = 2i,   2i+1   (i = 0..4)
    // w[g][i+5] covers k = 10+2i,11+2i
    f32x2 w[4][10];
    const float* wb = w_hh + d * (H_ * G_);
    #pragma unroll
    for (int g = 0; g < 4; ++g) {
        const float sc = (g == 2) ? 2.0f * LOG2E : -LOG2E;
        #pragma unroll
        for (int i = 0; i < 10; ++i)
            w[g][i] = mk2(sc * wb[(2 * i) * G_ + g * 20 + jj],
                          sc * wb[(2 * i + 1) * G_ + g * 20 + jj]);
    }

    // Wave-uniform h (SGPRs via readlane)
    float sh[20];
    #pragma unroll
    for (int k = 0; k < 20; ++k) sh[k] = 0.f;
    float c = 0.f;

    const int t0    = isB ? (T - 1) : 0;
    const int rstep = isB ? -160 : 160;
    const float* pf = xg + ((long long)(b * T + t0) * 2 + d) * 80 + 4 * jj;

    // transposed h store pointer: group of 4 t's, 16B aligned
    float* hp = h_out + ((long long)b * 40 + d * 20 + jj) * T + (isB ? T - 4 : 0);
    const int hgstep = isB ? -4 : 4;

    constexpr int PF = 8;
    float4 px[PF];
    #pragma unroll
    for (int s = 0; s < PF; ++s) { px[s] = *(const float4*)pf; pf += rstep; }

    float hq0 = 0.f, hq1 = 0.f, hq2 = 0.f, hq3 = 0.f;

    for (int tb = 0; tb < T; tb += PF) {
        #pragma unroll
        for (int s = 0; s < PF; ++s) {
            const float4 v = px[s];
            px[s] = *(const float4*)pf; pf += rstep;   // prefetch t+PF

            // 8 independent pk-chains: 4 gates x 2 k-halves, depth 5 each
            f32x2 aL[4], aH[4];
            aL[0] = mk2(v.x, 0.f); aL[1] = mk2(v.y, 0.f);
            aL[2] = mk2(v.z, 0.f); aL[3] = mk2(v.w, 0.f);
            #pragma unroll
            for (int g = 0; g < 4; ++g) aH[g] = mk2(0.f, 0.f);

            #pragma unroll
            for (int i = 0; i < 5; ++i) {
                const f32x2 hlo = mk2(sh[2 * i],      sh[2 * i + 1]);
                const f32x2 hhi = mk2(sh[10 + 2 * i], sh[11 + 2 * i]);
                #pragma unroll
                for (int g = 0; g < 4; ++g) {
                    aL[g] = __builtin_elementwise_fma(w[g][i],     hlo, aL[g]);
                    aH[g] = __builtin_elementwise_fma(w[g][i + 5], hhi, aH[g]);
                }
            }
            float m[4];
            #pragma unroll
            for (int g = 0; g < 4; ++g) {
                const f32x2 t2 = aL[g] + aH[g];
                m[g] = t2.x + t2.y;
            }

            const float gi = __builtin_amdgcn_rcpf(1.0f + __builtin_amdgcn_exp2f(m[0]));
            const float gf = __builtin_amdgcn_rcpf(1.0f + __builtin_amdgcn_exp2f(m[1]));
            const float gg = fmaf(-2.0f,
                __builtin_amdgcn_rcpf(1.0f + __builtin_amdgcn_exp2f(m[2])), 1.0f);
            const float go = __builtin_amdgcn_rcpf(1.0f + __builtin_amdgcn_exp2f(m[3]));

            c = fmaf(gf, c, gi * gg);
            const float th = fmaf(-2.0f,
                __builtin_amdgcn_rcpf(1.0f + __builtin_amdgcn_exp2f(2.0f * LOG2E * c)), 1.0f);
            const float hj = go * th;

            // buffer h (phase = s&3); one float4 store per 4 steps
            {
                const int p = s & 3;
                if (p == 0) hq0 = hj;
                else if (p == 1) hq1 = hj;
                else if (p == 2) hq2 = hj;
                else {
                    hq3 = hj;
                    float4 sv;   // bwd wrote t descending -> reverse for memory order
                    sv.x = isB ? hq3 : hq0;
                    sv.y = isB ? hq2 : hq1;
                    sv.z = isB ? hq1 : hq2;
                    sv.w = isB ? hq0 : hq3;
                    if (act_lane) *(float4*)hp = sv;
                    hp += hgstep;
                }
            }

            // broadcast h into wave-uniform SGPR copies (one direction only)
            #pragma unroll
            for (int k = 0; k < 20; ++k)
                sh[k] = __uint_as_float(__builtin_amdgcn_readlane(__float_as_uint(hj), k));
        }
    }
}

// ---------------------------------------------------------------------------
// FC over transposed h: out[b*T+t] = sum_u H1t[(b*40+u)*T+t]*w[u] + bias.
// ---------------------------------------------------------------------------
__global__ __launch_bounds__(256) void fc_t(
    const float* __restrict__ H1t,  // (B, 40, T)
    const float* __restrict__ Wf,   // (40,)
    const float* __restrict__ Bf,   // (1,)
    float* __restrict__ Out,        // (B, T)
    int T)
{
    const int b   = blockIdx.x;
    const int t   = blockIdx.y * 1024 + threadIdx.x * 4;
    if (t > T - 4) return;

    const float bias = Bf[0];
    float4 acc = make_float4(bias, bias, bias, bias);
    const float* base = H1t + (long long)b * 40 * T + t;
    #pragma unroll 8
    for (int u = 0; u < 40; ++u) {
        const float wv = Wf[u];
        const float4 hv = *(const float4*)(base + (long long)u * T);
        acc.x = fmaf(hv.x, wv, acc.x);
        acc.y = fmaf(hv.y, wv, acc.y);
        acc.z = fmaf(hv.z, wv, acc.z);
        acc.w = fmaf(hv.w, wv, acc.w);
    }
    *(float4*)(Out + (long long)b * T + t) = acc;
}

// ---------------------------------------------------------------------------
extern "C" void kernel_launch(void* const* d_in, const int* in_sizes, int n_in,
                              void* d_out, int out_size, void* d_ws, size_t ws_size,
                              hipStream_t stream) {
    const float* x     = (const float*)d_in[0];
    const float* wih0  = (const float*)d_in[1];
    const float* whh0  = (const float*)d_in[2];
    const float* b0    = (const float*)d_in[3];
    const float* wih1  = (const float*)d_in[4];
    const float* whh1  = (const float*)d_in[5];
    const float* b1    = (const float*)d_in[6];
    const float* fcw   = (const float*)d_in[7];
    const float* fcb   = (const float*)d_in[8];
    float* out = (float*)d_out;

    // Workspace (floats): 2048-float pads around xg for the scan's
    // unconditional ±8-step prefetch.
    float* ws = (float*)d_ws;
    float* xg  = ws + 2048;                  // B*T*2*80 = 81,920,000 floats
    float* h0t = xg + 81920000LL + 2048;     // B*40*T   = 20,480,000 floats
    float* h1t = h0t + 20480000LL;           // B*40*T   = 20,480,000 floats

    const int M = M_;
    const int gemm_grid = (M + 95) / 96;     // 5334

    // Layer 0 (row-major A)
    gemm_xg<80><<<dim3(gemm_grid), dim3(256), 0, stream>>>(x, wih0, b0, xg, M);
    lstm_scan<<<dim3(B_ * 2), dim3(64), 0, stream>>>(xg, whh0, h0t, T_);
    // Layer 1 (transposed A)
    gemm_xg_tA<<<dim3(B_ * 21), dim3(256), 0, stream>>>(h0t, wih1, b1, xg, T_);
    lstm_scan<<<dim3(B_ * 2), dim3(64), 0, stream>>>(xg, whh1, h1t, T_);
    // FC (transposed input, coalesced)
    fc_t<<<dim3(B_, 2), dim3(256), 0, stream>>>(h1t, fcw, fcb, out, T_);
}

// Round 4
// 1343.316 us; speedup vs baseline: 1.3852x; 1.1415x over previous
//
#include <hip/hip_runtime.h>
#include <math.h>

// Problem constants
#define B_ 256
#define T_ 2000
#define I_ 80
#define H_ 20
#define G_ 80      // 4*H
#define M_ 512000  // B*T

#define LOG2E 1.442695041f

typedef __attribute__((ext_vector_type(2))) float f32x2;
typedef __attribute__((ext_vector_type(2))) unsigned u32x2;

__device__ __forceinline__ f32x2 mk2(float a, float b) { f32x2 r; r.x = a; r.y = b; return r; }

// Cross-half value swap: returns, in lanes 0-31, the value held by lane+32
// (and in lanes 32-63, the value held by lane-32 / own value depending on
// path — only the low half's result is consumed).
__device__ __forceinline__ float swap_half(float x, int swapidx) {
#if __has_builtin(__builtin_amdgcn_permlane32_swap)
    u32x2 r = __builtin_amdgcn_permlane32_swap(__float_as_uint(x), __float_as_uint(x), false, false);
    return __uint_as_float(r.y);   // lanes<32: other half's value
#else
    (void)0;
    return __uint_as_float((unsigned)__builtin_amdgcn_ds_bpermute(swapidx, (int)__float_as_uint(x)));
#endif
}

// ---------------------------------------------------------------------------
// GEMM (layer 0, row-major A): XG[row][d*80 + j*4 + g] =
//   pS_g * (sum_k X[row][k]*Wih[d][k][g*20+j] + B[d][g*20+j])
// ---------------------------------------------------------------------------
template<int K>
__global__ __launch_bounds__(256) void gemm_xg(
    const float* __restrict__ X,     // (M, K) row-major
    const float* __restrict__ Wih,   // (2, K, 80)
    const float* __restrict__ Bias,  // (2, 80)
    float* __restrict__ XG,          // (M, 160) permuted+scaled cols
    int M)
{
    constexpr int KC = 40;
    __shared__ float ws[KC][164];
    __shared__ float xs[KC][100];
    __shared__ float bs[160];

    const int tid  = threadIdx.x;
    const int row0 = blockIdx.x * 96;
    const int tx = tid % 20;
    const int ty = tid / 20;
    const bool run = (ty < 12);

    if (tid < 160) {
        int dd = (tid >= 80);
        int r = tid - 80 * dd;
        int j = r >> 2, g = r & 3;
        float sc = (g == 2) ? 2.0f * LOG2E : -LOG2E;
        bs[tid] = sc * Bias[dd * 80 + g * 20 + j];
    }

    int nrows = M - row0; if (nrows > 96) nrows = 96;

    float acc[8][8];
    bool first = true;

    for (int kc = 0; kc < K; kc += KC) {
        for (int idx = tid; idx < KC * 160; idx += 256) {
            int i = idx / 160, cc = idx - 160 * i;
            int dd = (cc >= 80), r = cc - 80 * dd;
            int j = r >> 2, g = r & 3;
            float sc = (g == 2) ? 2.0f * LOG2E : -LOG2E;
            ws[i][cc] = sc * Wih[(dd * K + kc + i) * 80 + g * 20 + j];
        }
        for (int i4 = tid; i4 < (96 * KC) / 4; i4 += 256) {
            int r = i4 / 10;
            int kk = (i4 - 10 * r) * 4;
            float4 v = make_float4(0.f, 0.f, 0.f, 0.f);
            if (r < nrows)
                v = *(const float4*)(X + (long long)(row0 + r) * K + kc + kk);
            xs[kk][r] = v.x; xs[kk + 1][r] = v.y; xs[kk + 2][r] = v.z; xs[kk + 3][r] = v.w;
        }
        __syncthreads();

        if (first) {
            first = false;
            float bv[8];
            #pragma unroll
            for (int cc = 0; cc < 8; ++cc) bv[cc] = bs[tx * 8 + cc];
            #pragma unroll
            for (int r = 0; r < 8; ++r)
                #pragma unroll
                for (int cc = 0; cc < 8; ++cc) acc[r][cc] = bv[cc];
        }

        if (run) {
            #pragma unroll 4
            for (int k = 0; k < KC; ++k) {
                float a[8], bb[8];
                *(float4*)&a[0]  = *(const float4*)&xs[k][ty * 8];
                *(float4*)&a[4]  = *(const float4*)&xs[k][ty * 8 + 4];
                *(float4*)&bb[0] = *(const float4*)&ws[k][tx * 8];
                *(float4*)&bb[4] = *(const float4*)&ws[k][tx * 8 + 4];
                #pragma unroll
                for (int r = 0; r < 8; ++r)
                    #pragma unroll
                    for (int cc = 0; cc < 8; ++cc)
                        acc[r][cc] = fmaf(a[r], bb[cc], acc[r][cc]);
            }
        }
        __syncthreads();
    }

    if (run) {
        #pragma unroll
        for (int r = 0; r < 8; ++r) {
            int row = row0 + ty * 8 + r;
            if (row < M) {
                float* dst = XG + (long long)row * 160 + tx * 8;
                *(float4*)(dst)     = *(float4*)&acc[r][0];
                *(float4*)(dst + 4) = *(float4*)&acc[r][4];
            }
        }
    }
}

// ---------------------------------------------------------------------------
// GEMM (layer 1, TRANSPOSED A): A[row=(b,t)][k] = H0t[(b*40+k)*T + t]
// K=40. Tiles never straddle batches: grid = B * 21, tile = (b, t0..t0+95).
// ---------------------------------------------------------------------------
__global__ __launch_bounds__(256) void gemm_xg_tA(
    const float* __restrict__ H0t,   // (B, 40, T)
    const float* __restrict__ Wih,   // (2, 40, 80)
    const float* __restrict__ Bias,  // (2, 80)
    float* __restrict__ XG,          // (M, 160) permuted+scaled cols
    int T)
{
    constexpr int K = 40;
    __shared__ float ws[K][164];
    __shared__ float xs[K][100];
    __shared__ float bs[160];

    const int tid = threadIdx.x;
    const int bb  = blockIdx.x / 21;
    const int tc  = blockIdx.x % 21;
    const int t0  = tc * 96;
    const int tx  = tid % 20;
    const int ty  = tid / 20;
    const bool run = (ty < 12);

    if (tid < 160) {
        int dd = (tid >= 80);
        int r = tid - 80 * dd;
        int j = r >> 2, g = r & 3;
        float sc = (g == 2) ? 2.0f * LOG2E : -LOG2E;
        bs[tid] = sc * Bias[dd * 80 + g * 20 + j];
    }

    int nrows = T - t0; if (nrows > 96) nrows = 96;   // 96 or 80 (both %4==0)

    // stage weights (single K-chunk)
    for (int idx = tid; idx < K * 160; idx += 256) {
        int i = idx / 160, cc = idx - 160 * i;
        int dd = (cc >= 80), r = cc - 80 * dd;
        int j = r >> 2, g = r & 3;
        float sc = (g == 2) ? 2.0f * LOG2E : -LOG2E;
        ws[i][cc] = sc * Wih[(dd * K + i) * 80 + g * 20 + j];
    }
    // stage A^T: xs[k][r] = H0t[(bb*40+k)*T + t0 + r], float4 along r(=t)
    for (int i4 = tid; i4 < K * 24; i4 += 256) {
        int k = i4 / 24;
        int r = (i4 - 24 * k) * 4;
        float4 v = make_float4(0.f, 0.f, 0.f, 0.f);
        if (r < nrows)
            v = *(const float4*)(H0t + ((long long)bb * 40 + k) * T + t0 + r);
        *(float4*)&xs[k][r] = v;
    }
    __syncthreads();

    float acc[8][8];
    {
        float bv[8];
        #pragma unroll
        for (int cc = 0; cc < 8; ++cc) bv[cc] = bs[tx * 8 + cc];
        #pragma unroll
        for (int r = 0; r < 8; ++r)
            #pragma unroll
            for (int cc = 0; cc < 8; ++cc) acc[r][cc] = bv[cc];
    }

    if (run) {
        #pragma unroll 4
        for (int k = 0; k < K; ++k) {
            float a[8], bb2[8];
            *(float4*)&a[0]   = *(const float4*)&xs[k][ty * 8];
            *(float4*)&a[4]   = *(const float4*)&xs[k][ty * 8 + 4];
            *(float4*)&bb2[0] = *(const float4*)&ws[k][tx * 8];
            *(float4*)&bb2[4] = *(const float4*)&ws[k][tx * 8 + 4];
            #pragma unroll
            for (int r = 0; r < 8; ++r)
                #pragma unroll
                for (int cc = 0; cc < 8; ++cc)
                    acc[r][cc] = fmaf(a[r], bb2[cc], acc[r][cc]);
        }

        #pragma unroll
        for (int r = 0; r < 8; ++r) {
            int rr = ty * 8 + r;
            if (rr < nrows) {
                long long row = (long long)bb * T + t0 + rr;
                float* dst = XG + row * 160 + tx * 8;
                *(float4*)(dst)     = *(float4*)&acc[r][0];
                *(float4*)(dst + 4) = *(float4*)&acc[r][4];
            }
        }
    }
}

// ---------------------------------------------------------------------------
// LSTM scan v10: GATE-SPLIT ACROSS WAVE HALVES (one direction per wave).
//
// v9 was ISSUE-bound (~430cy/step of VALU issue; VALUBusy 36% = 72%/busy
// SIMD): only 20 of 64 lanes did gate work (40 pk-FMAs) and 10 trans ops
// issued per step. v10: lanes 0-19 own gates (i,f) of unit j, lanes 32-51
// own gates (g,o) of the SAME unit. One uniform instruction stream:
//   - pk-FMAs/step: 40 -> 20 (2 gates x 10 k-pairs per lane)
//   - trans/step:   10 -> 6 (shared sigma-core computes gi||sig(m_g) and
//                    gf||go in the two halves; +2 for tanh(c))
//   - 2 cross-half swaps (permlane32_swap; ds_bpermute fallback) bring
//     gg, go to the low half; c/tanh/h update identical to v9 there.
// Accumulation order is bit-identical to v9 -> absmax unchanged.
// ---------------------------------------------------------------------------
__attribute__((amdgpu_waves_per_eu(1, 1)))
__global__ __launch_bounds__(64) void lstm_scan(
    const float* __restrict__ xg,    // (B,T,2,20,4) scaled, unit-major
    const float* __restrict__ w_hh,  // (2, 20, 80) natural (k, g*20+j)
    float* __restrict__ h_out,       // (B, 40, T): [(b*40 + d*20 + j)*T + t]
    int T)
{
    const int bd   = blockIdx.x;          // 0..511
    const int b    = bd >> 1;
    const int d    = bd & 1;
    const int lane = threadIdx.x & 63;
    const int half = lane >> 5;           // 0: gates i,f   1: gates g,o
    const int j    = lane & 31;
    const bool act_lane = (lane < H_);    // lanes 0..19 hold h / store
    const int jj   = (j < H_) ? j : 0;
    const bool isB = (d == 1);

    const int swapidx = ((lane + 32) & 63) << 2;   // bpermute fallback index

    // Per-lane gates: A = (half? g : i), B = (half? o : f)
    const int gA = half ? 2 : 0;
    const int gB = gA + 1;
    const float scA = half ? (2.0f * LOG2E) : (-LOG2E);
    const float scB = -LOG2E;

    // Pre-scaled packed recurrent weights; k-pairs i=0..9 cover k=2i,2i+1.
    // Chains use wX[i] (k 0..9) and wX[i+5] (k 10..19), as in v9.
    f32x2 wA[10], wB[10];
    const float* wb = w_hh + d * (H_ * G_);
    #pragma unroll
    for (int i = 0; i < 10; ++i) {
        wA[i] = mk2(scA * wb[(2 * i) * G_ + gA * 20 + jj],
                    scA * wb[(2 * i + 1) * G_ + gA * 20 + jj]);
        wB[i] = mk2(scB * wb[(2 * i) * G_ + gB * 20 + jj],
                    scB * wb[(2 * i + 1) * G_ + gB * 20 + jj]);
    }

    // Wave-uniform h (SGPRs via readlane)
    float sh[20];
    #pragma unroll
    for (int k = 0; k < 20; ++k) sh[k] = 0.f;
    float c = 0.f;

    const int t0    = isB ? (T - 1) : 0;
    const int rstep = isB ? -160 : 160;
    // low half reads gates (0,1) = floats +0..1; high half gates (2,3) = +2..3
    const float* pf = xg + ((long long)(b * T + t0) * 2 + d) * 80 + 4 * jj + 2 * half;

    // transposed h store pointer: group of 4 t's, 16B aligned (low half stores)
    float* hp = h_out + ((long long)b * 40 + d * 20 + jj) * T + (isB ? T - 4 : 0);
    const int hgstep = isB ? -4 : 4;

    constexpr int PF = 8;
    f32x2 px[PF];
    #pragma unroll
    for (int s = 0; s < PF; ++s) { px[s] = *(const f32x2*)pf; pf += rstep; }

    float hq0 = 0.f, hq1 = 0.f, hq2 = 0.f, hq3 = 0.f;

    for (int tb = 0; tb < T; tb += PF) {
        #pragma unroll
        for (int s = 0; s < PF; ++s) {
            const f32x2 v = px[s];
            px[s] = *(const f32x2*)pf; pf += rstep;   // prefetch t+PF

            // 4 pk-chains: 2 gates x 2 k-halves, depth 5 each
            f32x2 aA1 = mk2(v.x, 0.f);
            f32x2 aA2 = mk2(0.f, 0.f);
            f32x2 aB1 = mk2(v.y, 0.f);
            f32x2 aB2 = mk2(0.f, 0.f);
            #pragma unroll
            for (int i = 0; i < 5; ++i) {
                const f32x2 hlo = mk2(sh[2 * i],      sh[2 * i + 1]);
                const f32x2 hhi = mk2(sh[10 + 2 * i], sh[11 + 2 * i]);
                aA1 = __builtin_elementwise_fma(wA[i],     hlo, aA1);
                aA2 = __builtin_elementwise_fma(wA[i + 5], hhi, aA2);
                aB1 = __builtin_elementwise_fma(wB[i],     hlo, aB1);
                aB2 = __builtin_elementwise_fma(wB[i + 5], hhi, aB2);
            }
            const f32x2 tA = aA1 + aA2;
            const f32x2 tB = aB1 + aB2;
            const float mA = tA.x + tA.y;    // low: m_i   high: m_g
            const float mB = tB.x + tB.y;    // low: m_f   high: m_o

            // shared sigma-core (both halves execute the same 4 trans ops)
            const float sA = __builtin_amdgcn_rcpf(1.0f + __builtin_amdgcn_exp2f(mA));
            const float sB = __builtin_amdgcn_rcpf(1.0f + __builtin_amdgcn_exp2f(mB));
            // low lanes: sA = gi, sB = gf.  high lanes: sA = sig(m_g), sB = go.

            // bring high half's values to the low half
            const float sAx = swap_half(sA, swapidx);  // low: sig(m_g) of own unit
            const float gox = swap_half(sB, swapidx);  // low: go of own unit

            const float gg = fmaf(-2.0f, sAx, 1.0f);   // low: tanh(g_raw)
            c = fmaf(sB, c, sA * gg);                  // low: gf*c + gi*gg
            const float th = fmaf(-2.0f,
                __builtin_amdgcn_rcpf(1.0f + __builtin_amdgcn_exp2f(2.0f * LOG2E * c)), 1.0f);
            const float hj = gox * th;                 // valid in lanes 0..19

            // buffer h (phase = s&3); one float4 store per 4 steps (low half)
            {
                const int p = s & 3;
                if (p == 0) hq0 = hj;
                else if (p == 1) hq1 = hj;
                else if (p == 2) hq2 = hj;
                else {
                    hq3 = hj;
                    float4 sv;   // bwd wrote t descending -> reverse for memory order
                    sv.x = isB ? hq3 : hq0;
                    sv.y = isB ? hq2 : hq1;
                    sv.z = isB ? hq1 : hq2;
                    sv.w = isB ? hq0 : hq3;
                    if (act_lane) *(float4*)hp = sv;
                    hp += hgstep;
                }
            }

            // broadcast h (lanes 0..19) into wave-uniform SGPR copies
            #pragma unroll
            for (int k = 0; k < 20; ++k)
                sh[k] = __uint_as_float(__builtin_amdgcn_readlane(__float_as_uint(hj), k));
        }
    }
}

// ---------------------------------------------------------------------------
// FC over transposed h: out[b*T+t] = sum_u H1t[(b*40+u)*T+t]*w[u] + bias.
// ---------------------------------------------------------------------------
__global__ __launch_bounds__(256) void fc_t(
    const float* __restrict__ H1t,  // (B, 40, T)
    const float* __restrict__ Wf,   // (40,)
    const float* __restrict__ Bf,   // (1,)
    float* __restrict__ Out,        // (B, T)
    int T)
{
    const int b   = blockIdx.x;
    const int t   = blockIdx.y * 1024 + threadIdx.x * 4;
    if (t > T - 4) return;

    const float bias = Bf[0];
    float4 acc = make_float4(bias, bias, bias, bias);
    const float* base = H1t + (long long)b * 40 * T + t;
    #pragma unroll 8
    for (int u = 0; u < 40; ++u) {
        const float wv = Wf[u];
        const float4 hv = *(const float4*)(base + (long long)u * T);
        acc.x = fmaf(hv.x, wv, acc.x);
        acc.y = fmaf(hv.y, wv, acc.y);
        acc.z = fmaf(hv.z, wv, acc.z);
        acc.w = fmaf(hv.w, wv, acc.w);
    }
    *(float4*)(Out + (long long)b * T + t) = acc;
}

// ---------------------------------------------------------------------------
extern "C" void kernel_launch(void* const* d_in, const int* in_sizes, int n_in,
                              void* d_out, int out_size, void* d_ws, size_t ws_size,
                              hipStream_t stream) {
    const float* x     = (const float*)d_in[0];
    const float* wih0  = (const float*)d_in[1];
    const float* whh0  = (const float*)d_in[2];
    const float* b0    = (const float*)d_in[3];
    const float* wih1  = (const float*)d_in[4];
    const float* whh1  = (const float*)d_in[5];
    const float* b1    = (const float*)d_in[6];
    const float* fcw   = (const float*)d_in[7];
    const float* fcb   = (const float*)d_in[8];
    float* out = (float*)d_out;

    // Workspace (floats): 2048-float pads around xg for the scan's
    // unconditional ±8-step prefetch.
    float* ws = (float*)d_ws;
    float* xg  = ws + 2048;                  // B*T*2*80 = 81,920,000 floats
    float* h0t = xg + 81920000LL + 2048;     // B*40*T   = 20,480,000 floats
    float* h1t = h0t + 20480000LL;           // B*40*T   = 20,480,000 floats

    const int M = M_;
    const int gemm_grid = (M + 95) / 96;     // 5334

    // Layer 0 (row-major A)
    gemm_xg<80><<<dim3(gemm_grid), dim3(256), 0, stream>>>(x, wih0, b0, xg, M);
    lstm_scan<<<dim3(B_ * 2), dim3(64), 0, stream>>>(xg, whh0, h0t, T_);
    // Layer 1 (transposed A)
    gemm_xg_tA<<<dim3(B_ * 21), dim3(256), 0, stream>>>(h0t, wih1, b1, xg, T_);
    lstm_scan<<<dim3(B_ * 2), dim3(64), 0, stream>>>(xg, whh1, h1t, T_);
    // FC (transposed input, coalesced)
    fc_t<<<dim3(B_, 2), dim3(256), 0, stream>>>(h1t, fcw, fcb, out, T_);
}